// Round 2
// baseline (11528.374 us; speedup 1.0000x reference)
//
#include <hip/hip_runtime.h>
#include <stdint.h>
#include <stdio.h>

#define ND 100000
#define NG 100000
#define NE 250000

typedef __attribute__((ext_vector_type(8))) short short8;
typedef __attribute__((ext_vector_type(4))) int   int4v;
typedef __attribute__((ext_vector_type(4))) float f32x4;

__device__ __forceinline__ float bf2f(short s) {
  union { unsigned u; float f; } v;
  v.u = ((unsigned)(unsigned short)s) << 16;
  return v.f;
}
__device__ __forceinline__ short f2bf_rne(float f) {
  union { float f; unsigned u; } v;
  v.f = f;
  unsigned u = v.u + 0x7FFFu + ((v.u >> 16) & 1u);
  return (short)(u >> 16);
}

// ---- dtype detection: flags[0]=features are f32, flags[1]=indices are int64 ----
__global__ void detect_kernel(const unsigned short* __restrict__ xs,
                              const int* __restrict__ idx, int* __restrict__ flags) {
  __shared__ int cnt_huge, cnt_oddnz;
  if (threadIdx.x == 0) { cnt_huge = 0; cnt_oddnz = 0; }
  __syncthreads();
  int t = threadIdx.x;
  int h = 0;
#pragma unroll
  for (int i = 0; i < 8; ++i) {
    unsigned e = ((unsigned)xs[t * 8 + i] >> 7) & 0xFFu;
    if (e >= 0xC0u) ++h;  // |v| >= 2^65 or Inf/NaN: impossible for N(0,1) bf16 data
  }
  if (h) atomicAdd(&cnt_huge, h);
  if (t < 128 && idx[2 * t + 1] != 0) atomicAdd(&cnt_oddnz, 1);
  __syncthreads();
  if (t == 0) {
    flags[0] = (cnt_huge > 8) ? 1 : 0;
    flags[1] = (cnt_oddnz == 0) ? 1 : 0;  // int64: odd words all zero (values < 2^31)
  }
}

// ---- degree histogram: deg[idx[e]] += 1 ----
__global__ void hist_kernel(const int* __restrict__ idx, float* __restrict__ deg,
                            const int* __restrict__ flags) {
  int t = blockIdx.x * blockDim.x + threadIdx.x;
  if (t < NE) {
    int v = flags[1] ? idx[2 * (size_t)t] : idx[t];
    atomicAdd(&deg[v], 1.0f);
  }
}

// ---- in-place deg -> rsqrt(max(deg,1)) ----
__global__ void norm_kernel(float* __restrict__ d, int n) {
  int t = blockIdx.x * blockDim.x + threadIdx.x;
  if (t < n) {
    float v = d[t];
    d[t] = rsqrtf(v < 1.0f ? 1.0f : v);
  }
}

// ---- VT[n,k] = 0.5 * sum_j Ws[k,j] * We[j,n]   (V = Ws@We, stored transposed, bf16)
__global__ void vt_kernel(const void* __restrict__ Ws, const void* __restrict__ We,
                          short* __restrict__ VT, int Kin, const int* __restrict__ flags) {
  int n = blockIdx.x * 256 + threadIdx.x;   // 0..511
  int k = blockIdx.y;                       // 0..Kin-1
  float acc = 0.f;
  if (flags[0]) {
    const float* wr = (const float*)Ws + (size_t)k * 512;
    const float* we = (const float*)We;
#pragma unroll 8
    for (int j = 0; j < 512; ++j) acc += wr[j] * we[(size_t)j * 512 + n];
  } else {
    const short* wr = (const short*)Ws + (size_t)k * 512;
    const short* we = (const short*)We;
#pragma unroll 8
    for (int j = 0; j < 512; ++j) acc += bf2f(wr[j]) * bf2f(we[(size_t)j * 512 + n]);
  }
  VT[(size_t)n * Kin + k] = f2bf_rne(0.5f * acc);
}

// ---- per-pair column vectors: c{1,2}[n]=0.5*(b_src@W_et)[n], cb[n]=0.5*(b_et1+b_et2)[n]
__global__ void cvec_kernel(const void* __restrict__ b1s, const void* __restrict__ W1,
                            const void* __restrict__ b2s, const void* __restrict__ W2,
                            const void* __restrict__ be1, const void* __restrict__ be2,
                            float* __restrict__ c1, float* __restrict__ c2,
                            float* __restrict__ cb, const int* __restrict__ flags) {
  int n = blockIdx.x * 256 + threadIdx.x;
  float a1 = 0.f, a2 = 0.f, vb1, vb2;
  if (flags[0]) {
    const float* B1 = (const float*)b1s; const float* M1 = (const float*)W1;
    const float* B2 = (const float*)b2s; const float* M2 = (const float*)W2;
    for (int j = 0; j < 512; ++j) {
      a1 += B1[j] * M1[(size_t)j * 512 + n];
      a2 += B2[j] * M2[(size_t)j * 512 + n];
    }
    vb1 = ((const float*)be1)[n]; vb2 = ((const float*)be2)[n];
  } else {
    const short* B1 = (const short*)b1s; const short* M1 = (const short*)W1;
    const short* B2 = (const short*)b2s; const short* M2 = (const short*)W2;
    for (int j = 0; j < 512; ++j) {
      a1 += bf2f(B1[j]) * bf2f(M1[(size_t)j * 512 + n]);
      a2 += bf2f(B2[j]) * bf2f(M2[(size_t)j * 512 + n]);
    }
    vb1 = bf2f(((const short*)be1)[n]); vb2 = bf2f(((const short*)be2)[n]);
  }
  c1[n] = 0.5f * a1;
  c2[n] = 0.5f * a2;
  cb[n] = 0.5f * (vb1 + vb2);
}

// ---- edge aggregation: y[dst] += nd[dst]*ns[src]*x[src]; s[dst] += nd*ns.  wave/edge ----
__global__ __launch_bounds__(256) void edge_agg(
    const void* __restrict__ x, const int* __restrict__ src, const int* __restrict__ dst,
    const float* __restrict__ ns, const float* __restrict__ nd,
    float* __restrict__ y, float* __restrict__ sv, int D, const int* __restrict__ flags) {
  int xf = flags[0], i64 = flags[1];
  int e = blockIdx.x * 4 + (threadIdx.x >> 6);   // grid = NE/4 exactly
  int lane = threadIdx.x & 63;
  int s = i64 ? src[2 * (size_t)e] : src[e];
  int d = i64 ? dst[2 * (size_t)e] : dst[e];
  float w = ns[s] * nd[d];
  if (lane == 0) atomicAdd(&sv[d], w);
  int c = lane << 3;                             // 8 elements per lane
  if (c < D) {
    float* yp = y + (size_t)d * D + c;
    float v[8];
    if (xf) {
      const float* xp = (const float*)x + (size_t)s * D + c;
      f32x4 q0 = *(const f32x4*)xp;
      f32x4 q1 = *(const f32x4*)(xp + 4);
#pragma unroll
      for (int i = 0; i < 4; ++i) { v[i] = q0[i]; v[4 + i] = q1[i]; }
    } else {
      const short* xp = (const short*)x + (size_t)s * D + c;
      int4v q = *(const int4v*)xp;
#pragma unroll
      for (int i = 0; i < 4; ++i) {
        unsigned u = (unsigned)q[i];
        union { unsigned u; float f; } lo, hi;
        lo.u = u << 16;
        hi.u = u & 0xFFFF0000u;
        v[2 * i] = lo.f; v[2 * i + 1] = hi.f;
      }
    }
#pragma unroll
    for (int i = 0; i < 8; ++i) atomicAdd(yp + i, v[i] * w);
  }
}

// ---- pair GEMM: out[m,n] = [A1|A2]@[B1;B2] (0.5 folded into B)
//                            + s1[m]*c1[n] + s2[m]*c2[n] + cb[n]   (f32 out)
// A1:[M,512] f32, A2:[M,256] f32, B1:[512,512] bf16 (B^T rowmajor), B2:[512,256]
__global__ __launch_bounds__(256) void pair_gemm(
    const float* __restrict__ A1, const float* __restrict__ A2,
    const short* __restrict__ B1, const short* __restrict__ B2,
    const float* __restrict__ s1, const float* __restrict__ s2,
    const float* __restrict__ c1, const float* __restrict__ c2,
    const float* __restrict__ cb, float* __restrict__ out, int M) {
  __shared__ __align__(16) float lds_a[128 * 68];   // 64 f32/row + 16B pad
  __shared__ __align__(16) short lds_b[128 * 72];   // 64 bf16/row + 16B pad
  const int tid = threadIdx.x;
  const int bn = blockIdx.x, bm = blockIdx.y;
  const int m0 = bm * 128, n0 = bn * 128;
  const int lane = tid & 63, wave = tid >> 6;
  const int wm = wave & 1, wn = wave >> 1;
  const int lr = lane & 15, lq = lane >> 4;

  f32x4 acc[4][4] = {};

  for (int st = 0; st < 12; ++st) {
    const float* Ap; const short* Bp; int K, k0;
    if (st < 8) { Ap = A1; Bp = B1; K = 512; k0 = st << 6; }
    else        { Ap = A2; Bp = B2; K = 256; k0 = (st - 8) << 6; }

    // stage A: 128 rows x 17 chunks(16B) = 2176 chunks (chunk 16 of each row = pad)
#pragma unroll
    for (int i = 0; i < 9; ++i) {
      int c = tid + i * 256;
      if (c < 2176) {
        int row = c / 17;
        int cc = c - row * 17; if (cc > 15) cc = 15;   // pad chunk: harmless dup load
        int rg = m0 + row; if (rg >= M) rg = M - 1;    // clamp tail rows
        const float* gp = Ap + (size_t)rg * K + (size_t)(k0 + (cc << 2));
        __builtin_amdgcn_global_load_lds(
            (const __attribute__((address_space(1))) void*)gp,
            (__attribute__((address_space(3))) void*)(lds_a + ((size_t)c << 2)),
            16, 0, 0);
      }
    }
    // stage B: 128 rows x 9 chunks(16B) = 1152 chunks
#pragma unroll
    for (int i = 0; i < 5; ++i) {
      int c = tid + i * 256;
      if (c < 1152) {
        int row = c / 9;
        int cc = c - row * 9; if (cc > 7) cc = 7;
        const short* gp = Bp + (size_t)(n0 + row) * K + (size_t)(k0 + (cc << 3));
        __builtin_amdgcn_global_load_lds(
            (const __attribute__((address_space(1))) void*)gp,
            (__attribute__((address_space(3))) void*)(lds_b + ((size_t)c << 3)),
            16, 0, 0);
      }
    }
    __syncthreads();

#pragma unroll
    for (int ks = 0; ks < 2; ++ks) {
      short8 bfrag[4];
#pragma unroll
      for (int ni = 0; ni < 4; ++ni) {
        int nl = wn * 64 + ni * 16 + lr;
        bfrag[ni] = *(const short8*)(lds_b + nl * 72 + ks * 32 + lq * 8);
      }
#pragma unroll
      for (int mi = 0; mi < 4; ++mi) {
        int ml = wm * 64 + mi * 16 + lr;
        const float* ap = lds_a + ml * 68 + ks * 32 + lq * 8;
        int4v q0 = *(const int4v*)ap;
        int4v q1 = *(const int4v*)(ap + 4);
        // pack 8 f32 -> 8 bf16 (truncate; error sign randomized by B in the dot)
        unsigned p0 = __builtin_amdgcn_perm((unsigned)q0[1], (unsigned)q0[0], 0x07060302u);
        unsigned p1 = __builtin_amdgcn_perm((unsigned)q0[3], (unsigned)q0[2], 0x07060302u);
        unsigned p2 = __builtin_amdgcn_perm((unsigned)q1[1], (unsigned)q1[0], 0x07060302u);
        unsigned p3 = __builtin_amdgcn_perm((unsigned)q1[3], (unsigned)q1[2], 0x07060302u);
        union { int4v i; short8 s; } au;
        au.i = (int4v){(int)p0, (int)p1, (int)p2, (int)p3};
        short8 afrag = au.s;
#pragma unroll
        for (int ni = 0; ni < 4; ++ni)
          acc[mi][ni] = __builtin_amdgcn_mfma_f32_16x16x32_bf16(afrag, bfrag[ni], acc[mi][ni], 0, 0, 0);
      }
    }
    __syncthreads();
  }

  // epilogue: C/D layout col=lane&15, row=(lane>>4)*4+reg  [m89-verified]
  float ct1[4], ct2[4], ctb[4]; int gn[4];
#pragma unroll
  for (int ni = 0; ni < 4; ++ni) {
    int n = n0 + wn * 64 + ni * 16 + lr;
    gn[ni] = n; ct1[ni] = c1[n]; ct2[ni] = c2[n]; ctb[ni] = cb[n];
  }
#pragma unroll
  for (int mi = 0; mi < 4; ++mi) {
    int mb = m0 + wm * 64 + mi * 16 + (lq << 2);
#pragma unroll
    for (int r = 0; r < 4; ++r) {
      int m = mb + r;
      if (m < M) {
        float sv1 = s1[m], sv2 = s2[m];
        float* op = out + (size_t)m * 512;
#pragma unroll
        for (int ni = 0; ni < 4; ++ni)
          op[gn[ni]] = acc[mi][ni][r] + sv1 * ct1[ni] + sv2 * ct2[ni] + ctb[ni];
      }
    }
  }
}

// ---------------- workspace layout ----------------
static constexpr size_t OFF_Y_DD = 0;                                   // [ND,512] f32
static constexpr size_t OFF_Y_DG = OFF_Y_DD + (size_t)NG * 512 * 4;     // [NG,512] f32
static constexpr size_t OFF_Y_GD = OFF_Y_DG + (size_t)NG * 512 * 4;     // [ND,256] f32
static constexpr size_t OFF_Y_GG = OFF_Y_GD + (size_t)ND * 256 * 4;     // [NG,256] f32
static constexpr size_t OFF_VT_DD = OFF_Y_GG + (size_t)NG * 256 * 4;    // 512x512 bf16
static constexpr size_t OFF_VT_DG = OFF_VT_DD + 512 * 512 * 2;
static constexpr size_t OFF_VT_GD = OFF_VT_DG + 512 * 512 * 2;          // 512x256 bf16
static constexpr size_t OFF_VT_GG = OFF_VT_GD + 512 * 256 * 2;
static constexpr size_t OFF_NRM  = OFF_VT_GG + 512 * 256 * 2;           // 8 x 100000 f32
static constexpr size_t OFF_SV   = OFF_NRM + 8 * 400000;                // 4 x 100000 f32
static constexpr size_t OFF_CV   = OFF_SV + 4 * 400000;                 // 6 x 512 f32
static constexpr size_t OFF_FLG  = OFF_CV + 6 * 2048;                   // 2 x int
static constexpr size_t WS_NEED  = OFF_FLG + 64;

extern "C" void kernel_launch(void* const* d_in, const int* in_sizes, int n_in,
                              void* d_out, int out_size, void* d_ws, size_t ws_size,
                              hipStream_t stream) {
  const void* x_d    = d_in[0];
  const void* x_g    = d_in[1];
  const void* W_drug = d_in[2];
  const void* b_drug = d_in[3];
  const void* W_gene = d_in[4];
  const void* b_gene = d_in[5];
  const void* W_dd   = d_in[6];
  const void* b_dd   = d_in[7];
  const void* W_dg   = d_in[8];
  const void* b_dg   = d_in[9];
  const void* W_gd   = d_in[10];
  const void* b_gd   = d_in[11];
  const void* W_gg   = d_in[12];
  const void* b_gg   = d_in[13];
  const int* src_dd = (const int*)d_in[14];
  const int* dst_dd = (const int*)d_in[15];
  const int* src_dg = (const int*)d_in[16];
  const int* dst_dg = (const int*)d_in[17];
  const int* src_gd = (const int*)d_in[18];
  const int* dst_gd = (const int*)d_in[19];
  const int* src_gg = (const int*)d_in[20];
  const int* dst_gg = (const int*)d_in[21];

  if (ws_size < WS_NEED) {
    fprintf(stderr, "kernel_launch: ws too small: have %zu need %zu\n", ws_size, WS_NEED);
    return;
  }

  char* ws = (char*)d_ws;
  float* y_dd = (float*)(ws + OFF_Y_DD);
  float* y_dg = (float*)(ws + OFF_Y_DG);
  float* y_gd = (float*)(ws + OFF_Y_GD);
  float* y_gg = (float*)(ws + OFF_Y_GG);
  short* vt_dd = (short*)(ws + OFF_VT_DD);
  short* vt_dg = (short*)(ws + OFF_VT_DG);
  short* vt_gd = (short*)(ws + OFF_VT_GD);
  short* vt_gg = (short*)(ws + OFF_VT_GG);
  float* ns_dd = (float*)(ws + OFF_NRM + 0 * 400000);
  float* nd_dd = (float*)(ws + OFF_NRM + 1 * 400000);
  float* ns_dg = (float*)(ws + OFF_NRM + 2 * 400000);
  float* nd_dg = (float*)(ws + OFF_NRM + 3 * 400000);
  float* ns_gd = (float*)(ws + OFF_NRM + 4 * 400000);
  float* nd_gd = (float*)(ws + OFF_NRM + 5 * 400000);
  float* ns_gg = (float*)(ws + OFF_NRM + 6 * 400000);
  float* nd_gg = (float*)(ws + OFF_NRM + 7 * 400000);
  float* s_dd = (float*)(ws + OFF_SV + 0 * 400000);
  float* s_gd = (float*)(ws + OFF_SV + 1 * 400000);
  float* s_dg = (float*)(ws + OFF_SV + 2 * 400000);
  float* s_gg = (float*)(ws + OFF_SV + 3 * 400000);
  float* c1_drug = (float*)(ws + OFF_CV + 0 * 2048);
  float* c2_drug = (float*)(ws + OFF_CV + 1 * 2048);
  float* cb_drug = (float*)(ws + OFF_CV + 2 * 2048);
  float* c1_gene = (float*)(ws + OFF_CV + 3 * 2048);
  float* c2_gene = (float*)(ws + OFF_CV + 4 * 2048);
  float* cb_gene = (float*)(ws + OFF_CV + 5 * 2048);
  int* flags = (int*)(ws + OFF_FLG);

  float* out_drug = (float*)d_out;
  float* out_gene = out_drug + (size_t)ND * 512;

  // dtype detection first (independent of memsets)
  detect_kernel<<<1, 256, 0, stream>>>((const unsigned short*)x_d, src_dd, flags);

  // zero y buffers + deg/norm + s vectors
  hipMemsetAsync(ws + OFF_Y_DD, 0, OFF_VT_DD, stream);
  hipMemsetAsync(ws + OFF_NRM, 0, 12 * 400000, stream);

  // degrees (deg_out over src, deg_in over dst) -> in-place norms
  dim3 hb((NE + 255) / 256);
  hist_kernel<<<hb, 256, 0, stream>>>(src_dd, ns_dd, flags);
  hist_kernel<<<hb, 256, 0, stream>>>(dst_dd, nd_dd, flags);
  hist_kernel<<<hb, 256, 0, stream>>>(src_dg, ns_dg, flags);
  hist_kernel<<<hb, 256, 0, stream>>>(dst_dg, nd_dg, flags);
  hist_kernel<<<hb, 256, 0, stream>>>(src_gd, ns_gd, flags);
  hist_kernel<<<hb, 256, 0, stream>>>(dst_gd, nd_gd, flags);
  hist_kernel<<<hb, 256, 0, stream>>>(src_gg, ns_gg, flags);
  hist_kernel<<<hb, 256, 0, stream>>>(dst_gg, nd_gg, flags);
  norm_kernel<<<(800000 + 255) / 256, 256, 0, stream>>>(ns_dd, 800000);

  // combined weights V^T = 0.5*(W_src @ W_et)^T  and bias column vectors
  vt_kernel<<<dim3(2, 512), 256, 0, stream>>>(W_drug, W_dd, vt_dd, 512, flags);
  vt_kernel<<<dim3(2, 512), 256, 0, stream>>>(W_drug, W_dg, vt_dg, 512, flags);
  vt_kernel<<<dim3(2, 256), 256, 0, stream>>>(W_gene, W_gd, vt_gd, 256, flags);
  vt_kernel<<<dim3(2, 256), 256, 0, stream>>>(W_gene, W_gg, vt_gg, 256, flags);
  cvec_kernel<<<2, 256, 0, stream>>>(b_drug, W_dd, b_gene, W_gd, b_dd, b_gd,
                                     c1_drug, c2_drug, cb_drug, flags);
  cvec_kernel<<<2, 256, 0, stream>>>(b_drug, W_dg, b_gene, W_gg, b_dg, b_gg,
                                     c1_gene, c2_gene, cb_gene, flags);

  // edge aggregation (normalized scatter of raw x)
  dim3 eb(NE / 4);
  edge_agg<<<eb, 256, 0, stream>>>(x_d, src_dd, dst_dd, ns_dd, nd_dd, y_dd, s_dd, 512, flags);
  edge_agg<<<eb, 256, 0, stream>>>(x_g, src_gd, dst_gd, ns_gd, nd_gd, y_gd, s_gd, 256, flags);
  edge_agg<<<eb, 256, 0, stream>>>(x_d, src_dg, dst_dg, ns_dg, nd_dg, y_dg, s_dg, 512, flags);
  edge_agg<<<eb, 256, 0, stream>>>(x_g, src_gg, dst_gg, ns_gg, nd_gg, y_gg, s_gg, 256, flags);

  // fused pair GEMMs -> f32 outputs
  dim3 gg(4, (ND + 127) / 128);
  pair_gemm<<<gg, 256, 0, stream>>>(y_dd, y_gd, vt_dd, vt_gd, s_dd, s_gd,
                                    c1_drug, c2_drug, cb_drug, out_drug, ND);
  pair_gemm<<<gg, 256, 0, stream>>>(y_dg, y_gg, vt_dg, vt_gg, s_dg, s_gg,
                                    c1_gene, c2_gene, cb_gene, out_gene, NG);
}